// Round 3
// baseline (498.927 us; speedup 1.0000x reference)
//
#include <hip/hip_runtime.h>
#include <hip/hip_bf16.h>

// MHA forward: x[4,2048,1024] -> qkv GEMM -> flash attention (transposed
// S^T/O^T, P in registers, l via ones-row MFMA, software-pipelined staging)
// -> out proj. bf16 MFMA 16x16x32, fp32 accumulate.

typedef __attribute__((ext_vector_type(8))) short short8;
typedef __attribute__((ext_vector_type(4))) float f32x4;

#define GLD16(g, l)                                                            \
  __builtin_amdgcn_global_load_lds(                                            \
      (const __attribute__((address_space(1))) unsigned int*)(g),              \
      (__attribute__((address_space(3))) unsigned int*)(l), 16, 0, 0)

#define SCL2E 0.1803368801111204f /* 0.125 * log2(e), folded into W_q */
#define L2E 1.44269504088896340736f

__device__ __forceinline__ unsigned short f2b(float f) {
  union { float f; unsigned int u; } v; v.f = f;
  unsigned int u = v.u;
  return (unsigned short)((u + 0x7fffu + ((u >> 16) & 1u)) >> 16);
}
__device__ __forceinline__ unsigned int fbits(float f) {
  union { float f; unsigned int u; } v; v.f = f; return v.u;
}

// ---------------- elementwise fp32 -> bf16 ----------------
__global__ void cvt_bf16(const float* __restrict__ in, ushort* __restrict__ out, int n) {
  int i = (blockIdx.x * blockDim.x + threadIdx.x) * 4;
  if (i + 3 < n) {
    float4 f = *(const float4*)(in + i);
    ushort4 o;
    o.x = f2b(f.x); o.y = f2b(f.y); o.z = f2b(f.z); o.w = f2b(f.w);
    *(ushort4*)(out + i) = o;
  }
}

// ---------------- mask * log2e (fp32 copy) ----------------
__global__ void mask_scale(const float* __restrict__ in, float* __restrict__ out, int n) {
  int i = (blockIdx.x * blockDim.x + threadIdx.x) * 4;
  if (i + 3 < n) {
    float4 f = *(const float4*)(in + i);
    f.x *= L2E; f.y *= L2E; f.z *= L2E; f.w *= L2E;
    *(float4*)(out + i) = f;
  }
}

// ---------------- bias, q-part scaled by 0.125*log2e ----------------
__global__ void scale_bias_q(const float* __restrict__ b, float* __restrict__ out, int n) {
  int i = blockIdx.x * blockDim.x + threadIdx.x;
  if (i < n) out[i] = b[i] * (((i % 192) < 64) ? SCL2E : 1.0f);
}

// -------- W[K][N] fp32 -> Wt[N][K] bf16; QSCALE: scale q-cols --------
template <int QSCALE>
__global__ void transpose_cvt(const float* __restrict__ W, ushort* __restrict__ Wt,
                              int K, int N) {
  __shared__ float tile[64][65];
  int n0 = blockIdx.x * 64, k0 = blockIdx.y * 64;
  int tx = threadIdx.x & 63, ty = threadIdx.x >> 6;
#pragma unroll
  for (int i = 0; i < 64; i += 4)
    tile[ty + i][tx] = W[(size_t)(k0 + ty + i) * N + n0 + tx];
  __syncthreads();
#pragma unroll
  for (int i = 0; i < 64; i += 4) {
    int n = n0 + ty + i;
    float s = (QSCALE && ((n % 192) < 64)) ? SCL2E : 1.0f;
    Wt[(size_t)n * K + k0 + tx] = f2b(tile[tx][ty + i] * s);
  }
}

// ---------------- GEMM: C[M,N] = A[M,K] @ Bt[N,K]^T + bias ----------------
template <int OUTF32>
__global__ __launch_bounds__(256, 2) void gemm_bt_bias(
    const ushort* __restrict__ A, const ushort* __restrict__ Bt,
    const float* __restrict__ bias, void* __restrict__ Cout,
    int M, int N, int K) {
  __shared__ ushort As[128 * 64];
  __shared__ ushort Bs[128 * 64];
  const int lane = threadIdx.x & 63;
  const int wv = threadIdx.x >> 6;
  const int bm = blockIdx.y, bn = blockIdx.x;
  const int wm = wv >> 1, wn = wv & 1;
  f32x4 acc[4][4] = {};
  const size_t arow0 = (size_t)bm * 128;
  const size_t brow0 = (size_t)bn * 128;

  for (int k0 = 0; k0 < K; k0 += 64) {
    __syncthreads();
#pragma unroll
    for (int i = 0; i < 4; ++i) {
      int r = wv * 32 + i * 8 + (lane >> 3);
      const ushort* ga = A + (arow0 + r) * K + k0 + (lane & 7) * 8;
      GLD16(ga, As + (wv * 32 + i * 8) * 64);
      const ushort* gb = Bt + (brow0 + r) * K + k0 + (lane & 7) * 8;
      GLD16(gb, Bs + (wv * 32 + i * 8) * 64);
    }
    __syncthreads();
    short8 af[2][4], bf[2][4];
#pragma unroll
    for (int kf = 0; kf < 2; ++kf)
#pragma unroll
      for (int t = 0; t < 4; ++t) {
        af[kf][t] = *(const short8*)(As + (wm * 64 + t * 16 + (lane & 15)) * 64 +
                                     kf * 32 + (lane >> 4) * 8);
        bf[kf][t] = *(const short8*)(Bs + (wn * 64 + t * 16 + (lane & 15)) * 64 +
                                     kf * 32 + (lane >> 4) * 8);
      }
#pragma unroll
    for (int kf = 0; kf < 2; ++kf)
#pragma unroll
      for (int mt = 0; mt < 4; ++mt)
#pragma unroll
        for (int nt = 0; nt < 4; ++nt)
          acc[mt][nt] = __builtin_amdgcn_mfma_f32_16x16x32_bf16(
              af[kf][mt], bf[kf][nt], acc[mt][nt], 0, 0, 0);
  }
#pragma unroll
  for (int nt = 0; nt < 4; ++nt) {
    int col = bn * 128 + wn * 64 + nt * 16 + (lane & 15);
    float bv = bias[col];
#pragma unroll
    for (int mt = 0; mt < 4; ++mt) {
      int row0 = bm * 128 + wm * 64 + mt * 16 + (lane >> 4) * 4;
#pragma unroll
      for (int r = 0; r < 4; ++r) {
        float v = acc[mt][nt][r] + bv;
        if (OUTF32)
          ((float*)Cout)[(size_t)(row0 + r) * N + col] = v;
        else
          ((ushort*)Cout)[(size_t)(row0 + r) * N + col] = f2b(v);
      }
    }
  }
}

// ---------------- flash attention (pipelined, transposed) ----------------
__global__ __launch_bounds__(256, 3) void flash_attn(
    const ushort* __restrict__ qkv, const float* __restrict__ maskl2e,
    float* __restrict__ values_f, ushort* __restrict__ values_b) {
  __shared__ ushort Ks[2][128 * 64];  // double-buffered, swizzled chunks
  __shared__ ushort Vt[64 * 136];     // V^T, permuted key cols, stride 136

  const int lane = threadIdx.x & 63;
  const int wv = threadIdx.x >> 6;
  const int c = lane & 15;  // q within 16-tile
  const int g = lane >> 4;  // quarter group
  const int z = blockIdx.x;
  const int qt = z >> 6;    // qt-major: blocks sharing mask tile co-resident
  const int bh = z & 63;
  const int b = bh >> 4, h = bh & 15;
  const size_t rowbase = (size_t)b * 2048;
  const int qcol = h * 192;
  const int swz = (c & 3) << 1;
  const int gcol = (((lane & 7) ^ (((lane >> 3) & 3) << 1)) << 3);

  // Q b-frags (W_q pre-scaled by 0.125*log2e)
  short8 qf[2][2];
#pragma unroll
  for (int mt = 0; mt < 2; ++mt)
#pragma unroll
    for (int kf = 0; kf < 2; ++kf)
      qf[mt][kf] = *(const short8*)(qkv +
          (rowbase + qt * 128 + wv * 32 + mt * 16 + c) * 3072 + qcol +
          kf * 32 + g * 8);

  f32x4 acc[2][4] = {};
  f32x4 lacc[2] = {};
  float mst[2] = {-3e38f, -3e38f};

  short8 ones8;
#pragma unroll
  for (int e = 0; e < 8; ++e) ones8[e] = (short)0x3f80;

  // V staging: thread -> key pair (K0,K0+1), d-quarter dq
  const int kp = threadIdx.x & 63, dq = threadIdx.x >> 6;
  const int K0 = kp * 2;
  const int pc0 = ((K0 >> 5) << 5) + (((K0 >> 2) & 3) << 3) +
                  (((K0 >> 4) & 1) << 2) + (K0 & 3);
  const int vdw = pc0 >> 1;

  const float* mrow = maskl2e + (size_t)(qt * 128 + wv * 32 + c) * 2048 + g * 4;

  short8 va0, va1, vb0, vb1;  // V prefetch registers

  // ---- prologue: stage kt=0 ----
  {
#pragma unroll
    for (int i = 0; i < 4; ++i) {
      int rloc = wv * 32 + i * 8;
      const ushort* gk =
          qkv + (rowbase + rloc + (lane >> 3)) * 3072 + qcol + 64 + gcol;
      GLD16(gk, &Ks[0][rloc * 64]);
    }
    const ushort* vg = qkv + (rowbase + K0) * 3072 + qcol + 128 + dq * 16;
    va0 = *(const short8*)(vg);
    va1 = *(const short8*)(vg + 8);
    vb0 = *(const short8*)(vg + 3072);
    vb1 = *(const short8*)(vg + 3072 + 8);
    __syncthreads();  // drain GLD + V loads
    unsigned int* Vdw = (unsigned int*)Vt;
#pragma unroll
    for (int j = 0; j < 8; ++j)
      Vdw[(dq * 16 + j) * 68 + vdw] =
          ((unsigned int)(unsigned short)vb0[j] << 16) | (unsigned short)va0[j];
#pragma unroll
    for (int j = 0; j < 8; ++j)
      Vdw[(dq * 16 + 8 + j) * 68 + vdw] =
          ((unsigned int)(unsigned short)vb1[j] << 16) | (unsigned short)va1[j];
    __syncthreads();
  }

  for (int kt = 0; kt < 16; ++kt) {
    const int cur = kt & 1;
    // ---- prefetch kt+1 (K -> other LDS buf, V -> regs) ----
    if (kt < 15) {
#pragma unroll
      for (int i = 0; i < 4; ++i) {
        int rloc = wv * 32 + i * 8;
        const ushort* gk = qkv +
            (rowbase + (kt + 1) * 128 + rloc + (lane >> 3)) * 3072 + qcol + 64 + gcol;
        GLD16(gk, &Ks[cur ^ 1][rloc * 64]);
      }
      const ushort* vg =
          qkv + (rowbase + (kt + 1) * 128 + K0) * 3072 + qcol + 128 + dq * 16;
      va0 = *(const short8*)(vg);
      va1 = *(const short8*)(vg + 8);
      vb0 = *(const short8*)(vg + 3072);
      vb1 = *(const short8*)(vg + 3072 + 8);
    }

    const float* mkt = mrow + kt * 128;
    float4 msk0[8];
#pragma unroll
    for (int nt = 0; nt < 8; ++nt) msk0[nt] = *(const float4*)(mkt + nt * 16);

    // ---- S^T = K . Q^T ----
    f32x4 sc[2][8];
#pragma unroll
    for (int nt = 0; nt < 8; ++nt) {
      short8 k0 = *(const short8*)(&Ks[cur][(nt * 16 + c) * 64 + ((g ^ swz) << 3)]);
      short8 k1 = *(const short8*)(&Ks[cur][(nt * 16 + c) * 64 + (((4 + g) ^ swz) << 3)]);
      f32x4 zz = {0.f, 0.f, 0.f, 0.f};
      sc[0][nt] = __builtin_amdgcn_mfma_f32_16x16x32_bf16(k0, qf[0][0], zz, 0, 0, 0);
      sc[0][nt] = __builtin_amdgcn_mfma_f32_16x16x32_bf16(k1, qf[0][1], sc[0][nt], 0, 0, 0);
      sc[1][nt] = __builtin_amdgcn_mfma_f32_16x16x32_bf16(k0, qf[1][0], zz, 0, 0, 0);
      sc[1][nt] = __builtin_amdgcn_mfma_f32_16x16x32_bf16(k1, qf[1][1], sc[1][nt], 0, 0, 0);
    }

    // ---- online softmax: t = sc + mask*log2e (already log2 units) ----
    __attribute__((aligned(16))) unsigned int Dw[2][16];
#pragma unroll
    for (int mt = 0; mt < 2; ++mt) {
      f32x4 t4[8];
#pragma unroll
      for (int nt = 0; nt < 8; ++nt) {
        float4 mk = (mt == 0) ? msk0[nt]
                              : *(const float4*)(mkt + 16 * 2048 + nt * 16);
#pragma unroll
        for (int r = 0; r < 4; ++r)
          t4[nt][r] = sc[mt][nt][r] + ((const float*)&mk)[r];
      }
      f32x4 vm = t4[0];
#pragma unroll
      for (int nt = 1; nt < 8; ++nt)
#pragma unroll
        for (int r = 0; r < 4; ++r) vm[r] = fmaxf(vm[r], t4[nt][r]);
      float pm = fmaxf(fmaxf(vm[0], vm[1]), fmaxf(vm[2], vm[3]));
      pm = fmaxf(pm, __shfl_xor(pm, 16));
      pm = fmaxf(pm, __shfl_xor(pm, 32));
      float mnew = fmaxf(mst[mt], pm);
      float alpha = exp2f(mst[mt] - mnew);
      mst[mt] = mnew;
#pragma unroll
      for (int nt = 0; nt < 8; ++nt) {
        unsigned int p0 = fbits(exp2f(t4[nt][0] - mnew));
        unsigned int p1 = fbits(exp2f(t4[nt][1] - mnew));
        unsigned int p2 = fbits(exp2f(t4[nt][2] - mnew));
        unsigned int p3 = fbits(exp2f(t4[nt][3] - mnew));
        Dw[mt][nt * 2 + 0] = __builtin_amdgcn_perm(p1, p0, 0x07060302u);
        Dw[mt][nt * 2 + 1] = __builtin_amdgcn_perm(p3, p2, 0x07060302u);
      }
#pragma unroll
      for (int dt = 0; dt < 4; ++dt)
#pragma unroll
        for (int r = 0; r < 4; ++r) acc[mt][dt][r] *= alpha;
      lacc[mt][0] *= alpha;
    }

    // ---- O^T += V^T . P^T ; l via ones-row MFMA ----
    const short8* bu0 = (const short8*)Dw[0];
    const short8* bu1 = (const short8*)Dw[1];
#pragma unroll
    for (int dt = 0; dt < 4; ++dt)
#pragma unroll
      for (int kf = 0; kf < 4; ++kf) {
        short8 vf = *(const short8*)(Vt + (dt * 16 + c) * 136 + kf * 32 + g * 8);
        acc[0][dt] = __builtin_amdgcn_mfma_f32_16x16x32_bf16(vf, bu0[kf], acc[0][dt], 0, 0, 0);
        acc[1][dt] = __builtin_amdgcn_mfma_f32_16x16x32_bf16(vf, bu1[kf], acc[1][dt], 0, 0, 0);
      }
#pragma unroll
    for (int kf = 0; kf < 4; ++kf) {
      lacc[0] = __builtin_amdgcn_mfma_f32_16x16x32_bf16(ones8, bu0[kf], lacc[0], 0, 0, 0);
      lacc[1] = __builtin_amdgcn_mfma_f32_16x16x32_bf16(ones8, bu1[kf], lacc[1], 0, 0, 0);
    }

    __syncthreads();  // all waves done with Vt; prefetched loads drained
    if (kt < 15) {
      unsigned int* Vdw = (unsigned int*)Vt;
#pragma unroll
      for (int j = 0; j < 8; ++j)
        Vdw[(dq * 16 + j) * 68 + vdw] =
            ((unsigned int)(unsigned short)vb0[j] << 16) | (unsigned short)va0[j];
#pragma unroll
      for (int j = 0; j < 8; ++j)
        Vdw[(dq * 16 + 8 + j) * 68 + vdw] =
            ((unsigned int)(unsigned short)vb1[j] << 16) | (unsigned short)va1[j];
      __syncthreads();
    }
  }

  // ---- epilogue: O^T col=q, rows d = dt*16 + g*4 + r; l from lacc ----
#pragma unroll
  for (int mt = 0; mt < 2; ++mt) {
    float rl = 1.0f / lacc[mt][0];
    size_t qrow = rowbase + qt * 128 + wv * 32 + mt * 16 + c;
#pragma unroll
    for (int dt = 0; dt < 4; ++dt) {
      int d0 = h * 64 + dt * 16 + g * 4;
      float4 o;
      o.x = acc[mt][dt][0] * rl; o.y = acc[mt][dt][1] * rl;
      o.z = acc[mt][dt][2] * rl; o.w = acc[mt][dt][3] * rl;
      *(float4*)(values_f + qrow * 1024 + d0) = o;
      ushort4 ob;
      ob.x = f2b(o.x); ob.y = f2b(o.y); ob.z = f2b(o.z); ob.w = f2b(o.w);
      *(ushort4*)(values_b + qrow * 1024 + d0) = ob;
    }
  }
}

extern "C" void kernel_launch(void* const* d_in, const int* in_sizes, int n_in,
                              void* d_out, int out_size, void* d_ws, size_t ws_size,
                              hipStream_t stream) {
  const float* x    = (const float*)d_in[0];
  const float* mask = (const float*)d_in[1];
  const float* Wqkv = (const float*)d_in[2];
  const float* bqkv = (const float*)d_in[3];
  const float* Wo   = (const float*)d_in[4];
  const float* bo   = (const float*)d_in[5];
  float* out      = (float*)d_out;
  float* values_f = out + 8388608;

  char* ws = (char*)d_ws;
  ushort* xb    = (ushort*)(ws + 0);          // 16 MB: x bf16, then mask*log2e fp32
  float*  mpre  = (float*)(ws + 0);
  ushort* wqkvt = (ushort*)(ws + 16777216);   // 6 MB   W_qkv^T bf16 (q cols scaled)
  ushort* wot   = (ushort*)(ws + 23068672);   // 2 MB   W_o^T bf16
  ushort* qkv   = (ushort*)(ws + 25165824);   // 48 MB  qkv bf16
  ushort* valb  = (ushort*)(ws + 75497472);   // 16 MB  values bf16
  float*  biass = (float*)(ws + 75497472);    // 12 KB scaled b_qkv (overwritten by flash later)

  cvt_bf16<<<dim3(8192), dim3(256), 0, stream>>>(x, xb, 8388608);
  transpose_cvt<1><<<dim3(48, 16), dim3(256), 0, stream>>>(Wqkv, wqkvt, 1024, 3072);
  transpose_cvt<0><<<dim3(16, 16), dim3(256), 0, stream>>>(Wo, wot, 1024, 1024);
  scale_bias_q<<<dim3(12), dim3(256), 0, stream>>>(bqkv, biass, 3072);
  gemm_bt_bias<0><<<dim3(24, 64), dim3(256), 0, stream>>>(
      xb, wqkvt, biass, (void*)qkv, 8192, 3072, 1024);
  mask_scale<<<dim3(4096), dim3(256), 0, stream>>>(mask, mpre, 4194304);
  flash_attn<<<dim3(1024), dim3(256), 0, stream>>>(qkv, mpre, values_f, valb);
  gemm_bt_bias<1><<<dim3(8, 64), dim3(256), 0, stream>>>(
      valb, wot, bo, (void*)out, 8192, 1024, 1024);
}